// Round 8
// baseline (1937.691 us; speedup 1.0000x reference)
//
#include <hip/hip_runtime.h>

#define M_TOTAL 65536   // B*T rows
#define DDIM    128     // latent dim (GEMM K)
#define KCODES  1024    // codebook size (GEMM N)
#define NQ      8       // RVQ stages
#define RROWS   128     // rows per block (4 waves x 32 rows)
#define TAU     0.15f   // margin threshold (validated rounds 5-7, absmax 0)

typedef _Float16 half8 __attribute__((ext_vector_type(8)));
typedef float    f32x4 __attribute__((ext_vector_type(4)));

// ---------------- ||e||^2 (verified round-1 semantics) ----------------
__global__ __launch_bounds__(256) void enorm_kernel(const float* __restrict__ embed,
                                                    float* __restrict__ enorm) {
  int c = blockIdx.x * 4 + (threadIdx.x >> 6);
  int lane = threadIdx.x & 63;
  const float* e = embed + (size_t)c * DDIM;
  float v0 = e[lane];
  float v1 = e[lane + 64];
  float s = fmaf(v0, v0, v1 * v1);
  #pragma unroll
  for (int off = 32; off > 0; off >>= 1) s += __shfl_down(s, off);
  if (lane == 0) enorm[c] = s;
}

// ---------------- pack embed -> f16 in MFMA B-fragment order ----------------
// Ep[stage][ci][kc][lane=q*16+l15][8]: code = ci*16+l15, k = kc*32+q*8+j.
// Lane l of a wave reading chunk (ci,kc) loads Ep + (ci*4+kc)*512 + l*8 -> fully
// coalesced 1KB per instruction.
__global__ __launch_bounds__(256) void epack_kernel(const float* __restrict__ embed,
                                                    _Float16* __restrict__ Ep) {
  int g = blockIdx.x * 256 + threadIdx.x;   // 131072 half8s
  int stage = g >> 14;                      // 16384 half8 per stage
  int rem = g & 16383;
  int code = rem >> 4, oct = rem & 15;      // oct = k/8
  int kc = oct >> 2, qq = oct & 3;
  int ci = code >> 4, l15c = code & 15;
  const float* src = embed + ((size_t)stage * KCODES + code) * DDIM + oct * 8;
  float4 v0 = *(const float4*)src;
  float4 v1 = *(const float4*)(src + 4);
  half8 h;
  h[0] = (_Float16)v0.x; h[1] = (_Float16)v0.y; h[2] = (_Float16)v0.z; h[3] = (_Float16)v0.w;
  h[4] = (_Float16)v1.x; h[5] = (_Float16)v1.y; h[6] = (_Float16)v1.z; h[7] = (_Float16)v1.w;
  size_t dst = ((((size_t)stage * 64 + ci) * 4 + kc) * 4 + qq) * 16 + l15c;
  *(half8*)(Ep + dst * 8) = h;
}

// ---------------- one RVQ stage: barrier-free f16 MFMA screen + in-block fixup ----
// 4 waves x 32 rows; each wave streams ALL 1024 codes' B-frags from L2 (packed
// layout), register double-buffered, NO LDS/barriers in the K-loop. Per-row
// top-2 margin; rows with margin <= TAU get an exact fp32 in-block recheck
// (round-1-verified fmaf-chain semantics). Then codes + exact f32 residual.
__global__ __launch_bounds__(256, 2) void rvq_stage(
    const float* __restrict__ rin, float* __restrict__ rout,
    const _Float16* __restrict__ EpS,       // packed f16 codebook, this stage
    const float* __restrict__ embedS,       // [KCODES][DDIM] fp32, this stage
    const float* __restrict__ enormS,       // [KCODES]
    int* __restrict__ codesS,               // [M_TOTAL] this stage
    int write_resid)
{
  __shared__ int   bcode[RROWS];
  __shared__ int   flagged[RROWS];
  __shared__ int   nflag;
  __shared__ float rowbuf[DDIM];
  __shared__ float fv[256];
  __shared__ int   fidx[256];

  const int tid = threadIdx.x;
  const int wv = tid >> 6;
  const int l  = tid & 63;
  const int l15 = l & 15;
  const int q = l >> 4;
  const int row_base = blockIdx.x * RROWS;

  if (tid == 0) nflag = 0;

  // ---- build f16 A-frags from global (once): af[rt][kc], A[m=l15][k=q*8+j] ----
  half8 af[2][4];
  #pragma unroll
  for (int rt = 0; rt < 2; ++rt) {
    const float* pa = rin + (size_t)(row_base + wv * 32 + rt * 16 + l15) * DDIM;
    #pragma unroll
    for (int kc = 0; kc < 4; ++kc) {
      float4 x0 = *(const float4*)(pa + kc * 32 + q * 8);
      float4 x1 = *(const float4*)(pa + kc * 32 + q * 8 + 4);
      half8 h;
      h[0] = (_Float16)x0.x; h[1] = (_Float16)x0.y; h[2] = (_Float16)x0.z; h[3] = (_Float16)x0.w;
      h[4] = (_Float16)x1.x; h[5] = (_Float16)x1.y; h[6] = (_Float16)x1.z; h[7] = (_Float16)x1.w;
      af[rt][kc] = h;
    }
  }

  float v1[8], v2[8];
  int i1[8];
  #pragma unroll
  for (int s = 0; s < 8; ++s) { v1[s] = -3.0e38f; v2[s] = -3.0e38f; i1[s] = 0x7fffffff; }

  // branchless top-2 update for one 16-code chunk (codes ascend -> strict >
  // keeps first occurrence; exact ties give margin 0 <= TAU -> exact fixup).
  auto upd = [&](int ci, float en, const f32x4& A0, const f32x4& A1) {
    int cgi = ci * 16 + l15;
    #pragma unroll
    for (int reg = 0; reg < 4; ++reg) {
      float d0 = fmaf(2.0f, A0[reg], -en);
      v2[reg] = fmaxf(v2[reg], fminf(d0, v1[reg]));
      if (d0 > v1[reg]) i1[reg] = cgi;
      v1[reg] = fmaxf(v1[reg], d0);
      float d1 = fmaf(2.0f, A1[reg], -en);
      v2[4 + reg] = fmaxf(v2[4 + reg], fminf(d1, v1[4 + reg]));
      if (d1 > v1[4 + reg]) i1[4 + reg] = cgi;
      v1[4 + reg] = fmaxf(v1[4 + reg], d1);
    }
  };

  // ---- barrier-free K-loop: 64 chunks of 16 codes, reg double-buffered ----
  const _Float16* ep = EpS + l * 8;
  half8 bfA[4], bfB[4];
  #pragma unroll
  for (int kc = 0; kc < 4; ++kc) bfA[kc] = *(const half8*)(ep + kc * 512);

  for (int cp = 0; cp < 32; ++cp) {
    const int ci0 = 2 * cp, ci1 = 2 * cp + 1;
    #pragma unroll
    for (int kc = 0; kc < 4; ++kc)
      bfB[kc] = *(const half8*)(ep + ((size_t)(ci1 * 4 + kc)) * 512);
    float en0 = enormS[ci0 * 16 + l15];
    float en1 = enormS[ci1 * 16 + l15];

    f32x4 a0 = (f32x4){0.f, 0.f, 0.f, 0.f}, a1 = (f32x4){0.f, 0.f, 0.f, 0.f};
    #pragma unroll
    for (int kc = 0; kc < 4; ++kc) {
      a0 = __builtin_amdgcn_mfma_f32_16x16x32_f16(af[0][kc], bfA[kc], a0, 0, 0, 0);
      a1 = __builtin_amdgcn_mfma_f32_16x16x32_f16(af[1][kc], bfA[kc], a1, 0, 0, 0);
    }
    upd(ci0, en0, a0, a1);

    if (cp < 31) {
      #pragma unroll
      for (int kc = 0; kc < 4; ++kc)
        bfA[kc] = *(const half8*)(ep + ((size_t)((ci0 + 2) * 4 + kc)) * 512);
    }

    a0 = (f32x4){0.f, 0.f, 0.f, 0.f}; a1 = (f32x4){0.f, 0.f, 0.f, 0.f};
    #pragma unroll
    for (int kc = 0; kc < 4; ++kc) {
      a0 = __builtin_amdgcn_mfma_f32_16x16x32_f16(af[0][kc], bfB[kc], a0, 0, 0, 0);
      a1 = __builtin_amdgcn_mfma_f32_16x16x32_f16(af[1][kc], bfB[kc], a1, 0, 0, 0);
    }
    upd(ci1, en1, a0, a1);
  }

  // ---- merge top-2 across the 16 l15-lanes sharing each row (disjoint codes) ----
  #pragma unroll
  for (int s = 0; s < 8; ++s) {
    #pragma unroll
    for (int off = 1; off < 16; off <<= 1) {
      float ov1 = __shfl_xor(v1[s], off);
      int   oi1 = __shfl_xor(i1[s], off);
      float ov2 = __shfl_xor(v2[s], off);
      if (ov1 > v1[s] || (ov1 == v1[s] && oi1 < i1[s])) {
        float nv2 = fmaxf(v1[s], ov2);
        v1[s] = ov1; i1[s] = oi1; v2[s] = nv2;
      } else {
        v2[s] = fmaxf(v2[s], ov1);
      }
    }
  }
  __syncthreads();   // orders nflag=0 before the flag atomics below

  if (l15 == 0) {
    #pragma unroll
    for (int s = 0; s < 8; ++s) {
      int row = wv * 32 + (s >> 2) * 16 + q * 4 + (s & 3);
      bcode[row] = i1[s];
      if (v1[s] - v2[s] <= TAU) {
        int pos = atomicAdd(&nflag, 1);
        flagged[pos] = row;
      }
    }
  }
  __syncthreads();

  // ---- in-block exact fixup for flagged rows (round-1-verified fp32 semantics) ----
  const int nfl = nflag;
  for (int f = 0; f < nfl; ++f) {
    const int r = flagged[f];
    const size_t gr = (size_t)(row_base + r);
    if (tid < 32)
      *(float4*)(rowbuf + tid * 4) = *(const float4*)(rin + gr * DDIM + tid * 4);
    __syncthreads();

    float acc[4];
    #pragma unroll
    for (int jc = 0; jc < 4; ++jc) acc[jc] = 0.f;
    for (int k4 = 0; k4 < 32; ++k4) {
      float4 rb = *(const float4*)(&rowbuf[k4 * 4]);
      #pragma unroll
      for (int jc = 0; jc < 4; ++jc) {
        float4 e4 = *(const float4*)(embedS + (size_t)(tid * 4 + jc) * DDIM + k4 * 4);
        acc[jc] = fmaf(rb.x, e4.x, acc[jc]);
        acc[jc] = fmaf(rb.y, e4.y, acc[jc]);
        acc[jc] = fmaf(rb.z, e4.z, acc[jc]);
        acc[jc] = fmaf(rb.w, e4.w, acc[jc]);
      }
    }
    float bv = -3.0e38f; int bi = 0x7fffffff;
    #pragma unroll
    for (int jc = 0; jc < 4; ++jc) {
      int c = tid * 4 + jc;
      float dd = 2.0f * acc[jc] - enormS[c];
      if (dd > bv) { bv = dd; bi = c; }   // jc ascending -> first occurrence
    }
    fv[tid] = bv; fidx[tid] = bi;
    __syncthreads();
    for (int step = 128; step > 0; step >>= 1) {
      if (tid < step) {
        float o = fv[tid + step]; int oi = fidx[tid + step];
        if (o > fv[tid] || (o == fv[tid] && oi < fidx[tid])) { fv[tid] = o; fidx[tid] = oi; }
      }
      __syncthreads();
    }
    if (tid == 0) bcode[r] = fidx[0];
    __syncthreads();
  }

  // ---- write codes; exact f32 residual update (block owns its rows) ----
  if (tid < RROWS) codesS[row_base + tid] = bcode[tid];
  __syncthreads();

  if (write_resid) {
    #pragma unroll
    for (int it = 0; it < 16; ++it) {
      int idx = it * 256 + tid;
      int r = idx >> 5, f4 = idx & 31;
      float4 e = *(const float4*)(embedS + (size_t)bcode[r] * DDIM + f4 * 4);
      float4 a = *(const float4*)(rin + (size_t)(row_base + r) * DDIM + f4 * 4);
      float4 o;
      o.x = a.x - e.x; o.y = a.y - e.y; o.z = a.z - e.z; o.w = a.w - e.w;
      *(float4*)(rout + (size_t)(row_base + r) * DDIM + f4 * 4) = o;
    }
  }
}

// ================= fallback: round-2 verified exact-fp32 kernel =================
#define F_NCHUNK  256
#define F_KC      16
#define F_AS_STRIDE 68
#define F_ES_STRIDE 260

__global__ __launch_bounds__(256, 3) void rvq_stage_kernel(
    const float* __restrict__ rin, float* __restrict__ rout,
    const float* __restrict__ embed, const float* __restrict__ enorm,
    int* __restrict__ codes)
{
  __shared__ float smem[DDIM * F_AS_STRIDE + F_KC * F_ES_STRIDE + F_NCHUNK];
  float* As  = smem;
  float* Es  = smem + DDIM * F_AS_STRIDE;
  float* Ens = Es + F_KC * F_ES_STRIDE;
  float* red_v = Es;
  int*   red_i = (int*)(Es + 64 * 33);
  int*   bcode = (int*)(Es + 2 * 64 * 33);

  const int tid = threadIdx.x;
  const int tx = tid & 31;
  const int ty = tid >> 5;
  const int row_base = blockIdx.x * 64;

  #pragma unroll
  for (int it = 0; it < 8; ++it) {
    int idx = it * 256 + tid;
    int r = idx >> 5, f4 = idx & 31;
    float4 v = *(const float4*)(rin + (size_t)(row_base + r) * DDIM + f4 * 4);
    As[(4 * f4 + 0) * F_AS_STRIDE + r] = v.x;
    As[(4 * f4 + 1) * F_AS_STRIDE + r] = v.y;
    As[(4 * f4 + 2) * F_AS_STRIDE + r] = v.z;
    As[(4 * f4 + 3) * F_AS_STRIDE + r] = v.w;
  }

  float best[8]; int bidx[8];
  #pragma unroll
  for (int i = 0; i < 8; ++i) { best[i] = -3.0e38f; bidx[i] = 0x7fffffff; }

  for (int nc = 0; nc < KCODES / F_NCHUNK; ++nc) {
    float acc[8][8];
    #pragma unroll
    for (int i = 0; i < 8; ++i)
      #pragma unroll
      for (int j = 0; j < 8; ++j) acc[i][j] = 0.0f;

    for (int kc = 0; kc < DDIM / F_KC; ++kc) {
      __syncthreads();
      #pragma unroll
      for (int it = 0; it < 4; ++it) {
        int idx = it * 256 + tid;
        int c = idx >> 2, f4 = idx & 3;
        float4 v = *(const float4*)(embed + (size_t)(nc * F_NCHUNK + c) * DDIM + kc * F_KC + f4 * 4);
        Es[(4 * f4 + 0) * F_ES_STRIDE + c] = v.x;
        Es[(4 * f4 + 1) * F_ES_STRIDE + c] = v.y;
        Es[(4 * f4 + 2) * F_ES_STRIDE + c] = v.z;
        Es[(4 * f4 + 3) * F_ES_STRIDE + c] = v.w;
      }
      if (kc == 0) Ens[tid] = enorm[nc * F_NCHUNK + tid];
      __syncthreads();

      const float* pa = As + kc * F_KC * F_AS_STRIDE + ty * 8;
      const float* pe = Es + 4 * tx;
      #pragma unroll 4
      for (int k = 0; k < F_KC; ++k) {
        float4 a0 = *(const float4*)(pa + k * F_AS_STRIDE);
        float4 a1 = *(const float4*)(pa + k * F_AS_STRIDE + 4);
        float4 e0 = *(const float4*)(pe + k * F_ES_STRIDE);
        float4 e1 = *(const float4*)(pe + k * F_ES_STRIDE + 128);
        float aa[8] = {a0.x, a0.y, a0.z, a0.w, a1.x, a1.y, a1.z, a1.w};
        float ee[8] = {e0.x, e0.y, e0.z, e0.w, e1.x, e1.y, e1.z, e1.w};
        #pragma unroll
        for (int i = 0; i < 8; ++i)
          #pragma unroll
          for (int j = 0; j < 8; ++j)
            acc[i][j] = fmaf(aa[i], ee[j], acc[i][j]);
      }
    }

    #pragma unroll
    for (int j = 0; j < 8; ++j) {
      int c_local = (j < 4) ? (4 * tx + j) : (128 + 4 * tx + (j - 4));
      float en = Ens[c_local];
      int cg = nc * F_NCHUNK + c_local;
      #pragma unroll
      for (int i = 0; i < 8; ++i) {
        float dist = 2.0f * acc[i][j] - en;
        if (dist > best[i] || (dist == best[i] && cg < bidx[i])) { best[i] = dist; bidx[i] = cg; }
      }
    }
  }

  __syncthreads();
  #pragma unroll
  for (int i = 0; i < 8; ++i) {
    red_v[(ty * 8 + i) * 33 + tx] = best[i];
    red_i[(ty * 8 + i) * 33 + tx] = bidx[i];
  }
  __syncthreads();
  if (tid < 64) {
    float bv = red_v[tid * 33]; int bi = red_i[tid * 33];
    #pragma unroll
    for (int t = 1; t < 32; ++t) {
      float v = red_v[tid * 33 + t]; int ix = red_i[tid * 33 + t];
      if (v > bv || (v == bv && ix < bi)) { bv = v; bi = ix; }
    }
    codes[row_base + tid] = bi;
    bcode[tid] = bi;
  }
  __syncthreads();
  #pragma unroll
  for (int it = 0; it < 32; ++it) {
    int idx = it * 256 + tid;
    int r = idx >> 7, d = idx & 127;
    float e = embed[(size_t)bcode[r] * DDIM + d];
    rout[(size_t)(row_base + r) * DDIM + d] = As[d * F_AS_STRIDE + r] - e;
  }
}

extern "C" void kernel_launch(void* const* d_in, const int* in_sizes, int n_in,
                              void* d_out, int out_size, void* d_ws, size_t ws_size,
                              hipStream_t stream) {
  (void)in_sizes; (void)n_in; (void)out_size;
  const float* x = (const float*)d_in[0];
  const float* embed = (const float*)d_in[1];
  int* codes = (int*)d_out;

  const size_t R_BYTES  = (size_t)M_TOTAL * DDIM * 4;             // 32 MB f32 residual
  const size_t EP_BYTES = (size_t)NQ * KCODES * DDIM * 2;         // 2 MB packed f16 codebook
  const size_t EN_BYTES = (size_t)NQ * KCODES * 4;                // 32 KB
  const size_t need = R_BYTES + EP_BYTES + EN_BYTES + 256;

  if (ws_size >= need) {
    char* w = (char*)d_ws;
    float* resid   = (float*)w;        w += R_BYTES;
    _Float16* Ep   = (_Float16*)w;     w += EP_BYTES;
    float* enorm   = (float*)w;

    enorm_kernel<<<dim3(NQ * KCODES / 4), dim3(256), 0, stream>>>(embed, enorm);
    epack_kernel<<<dim3(NQ * KCODES * DDIM / 8 / 256), dim3(256), 0, stream>>>(embed, Ep);

    for (int q = 0; q < NQ; ++q) {
      int wr = (q < NQ - 1) ? 1 : 0;
      const float* rin = (q == 0) ? x : resid;
      rvq_stage<<<dim3(M_TOTAL / RROWS), dim3(256), 0, stream>>>(
          rin, resid,
          Ep + (size_t)q * KCODES * DDIM,
          embed + (size_t)q * KCODES * DDIM,
          enorm + (size_t)q * KCODES,
          codes + (size_t)q * M_TOTAL, wr);
    }
  } else {
    // fallback: verified round-2 exact-fp32 path
    const size_t resid_elems = (size_t)M_TOTAL * DDIM;
    const bool ws_ok = ws_size >= (resid_elems + (size_t)NQ * KCODES) * sizeof(float);
    float* resid = ws_ok ? (float*)d_ws : (float*)d_in[0];
    float* enorm = ws_ok ? ((float*)d_ws + resid_elems) : (float*)d_ws;

    enorm_kernel<<<dim3(NQ * KCODES / 4), dim3(256), 0, stream>>>(embed, enorm);
    for (int q = 0; q < NQ; ++q) {
      const float* rin = (q == 0) ? x : resid;
      rvq_stage_kernel<<<dim3(M_TOTAL / 64), dim3(256), 0, stream>>>(
          rin, resid, embed + (size_t)q * KCODES * DDIM,
          enorm + (size_t)q * KCODES, codes + (size_t)q * M_TOTAL);
    }
  }
}